// Round 1
// baseline (572.309 us; speedup 1.0000x reference)
//
#include <hip/hip_runtime.h>

// ---------------------------------------------------------------------------
// LigerFusedNeighborhoodAttention on MI355X (gfx950)
// B=2, S=8192, H=1024, NH=16, HD=64, KERNEL=7, DILATION=1, SCALE=1/8
//
// Pipeline:
//   1. cast X fp32 -> bf16                         (memory-bound)
//   2. transpose+cast Wq/Wk/Wv -> WtQKV (3072,1024) bf16, Wo -> WtO
//   3. fused QKV GEMM  (16384 x 3072 x 1024) bf16 MFMA -> QKV bf16
//   4. neighborhood attention (one wave per query) -> attn out bf16
//   5. output GEMM (16384 x 1024 x 1024) -> d_out fp32
// GEMM = m97-style: 128x128 tile, 4 waves, BK=32, global_load_lds width 16.
// ---------------------------------------------------------------------------

typedef __bf16 bf16x8 __attribute__((ext_vector_type(8)));
typedef float f32x4 __attribute__((ext_vector_type(4)));
typedef __attribute__((address_space(1))) void as1_void;
typedef __attribute__((address_space(3))) void as3_void;

__device__ __forceinline__ float bf2f(unsigned short u) {
    union { unsigned int u; float f; } c;
    c.u = ((unsigned int)u) << 16;
    return c.f;
}
__device__ __forceinline__ unsigned short f2bf(float f) {
    union { float f; unsigned int u; } c;
    c.f = f;
    unsigned int u = c.u;
    u += 0x7fffu + ((u >> 16) & 1u);   // round-to-nearest-even
    return (unsigned short)(u >> 16);
}

// --------------------------- cast X fp32 -> bf16 ---------------------------
__global__ __launch_bounds__(256) void cast_kernel(
    const float* __restrict__ in, unsigned short* __restrict__ out, int n4) {
    int i = blockIdx.x * 256 + threadIdx.x;
    if (i < n4) {
        float4 v = ((const float4*)in)[i];
        ushort4 o;
        o.x = f2bf(v.x); o.y = f2bf(v.y); o.z = f2bf(v.z); o.w = f2bf(v.w);
        ((ushort4*)out)[i] = o;
    }
}

// ------------------- transpose+cast 1024x1024 W -> Wt bf16 -----------------
// Wt[c][r] = W[r][c]; grid (32,32), block (32,8)
__global__ __launch_bounds__(256) void transpose_cast(
    const float* __restrict__ W, unsigned short* __restrict__ Wt) {
    __shared__ unsigned short tile[32][33];
    const int c0 = blockIdx.x * 32;
    const int r0 = blockIdx.y * 32;
    const int tx = threadIdx.x;
    const int ty = threadIdx.y;
#pragma unroll
    for (int i = 0; i < 32; i += 8)
        tile[ty + i][tx] = f2bf(W[(size_t)(r0 + ty + i) * 1024 + c0 + tx]);
    __syncthreads();
#pragma unroll
    for (int i = 0; i < 32; i += 8)
        Wt[(size_t)(c0 + ty + i) * 1024 + r0 + tx] = tile[tx][ty + i];
}

// --------------------------- bias concat (3072) ----------------------------
__global__ __launch_bounds__(256) void concat_bias(
    const float* __restrict__ a, const float* __restrict__ b,
    const float* __restrict__ c, float* __restrict__ o) {
    int i = blockIdx.x * 256 + threadIdx.x;
    if (i < 3072)
        o[i] = (i < 1024) ? a[i] : ((i < 2048) ? b[i - 1024] : c[i - 2048]);
}

// ------------------------------- MFMA GEMM ---------------------------------
// C(M,N) = A(M,K) * Bt(N,K)^T + bias, A/Bt bf16 row-major, K%32==0, tiles 128.
// OUT_F32: 1 -> fp32 store to Cf, 0 -> bf16 store to Cb.
template <int OUT_F32>
__global__ __launch_bounds__(256) void gemm_bt(
    const unsigned short* __restrict__ A, const unsigned short* __restrict__ Bt,
    const float* __restrict__ bias, float* __restrict__ Cf,
    unsigned short* __restrict__ Cb, int N, int K) {
    __shared__ unsigned short sA[128 * 32];
    __shared__ unsigned short sB[128 * 32];
    const int tid = threadIdx.x;
    const int lane = tid & 63;
    const int wave = tid >> 6;
    const int bm = blockIdx.y * 128;
    const int bn = blockIdx.x * 128;
    const int wm = (wave >> 1) * 64;   // wave 2x2 -> 64x64 each
    const int wn = (wave & 1) * 64;
    const int quad = lane >> 4;
    const int mr = lane & 15;

    // staging: thread t covers 16B; LDS is filled in thread order (t*16 bytes)
    const unsigned short* gA0 = A + (size_t)(bm + (tid >> 2)) * K + (tid & 3) * 8;
    const unsigned short* gA1 = gA0 + (size_t)64 * K;
    const unsigned short* gB0 = Bt + (size_t)(bn + (tid >> 2)) * K + (tid & 3) * 8;
    const unsigned short* gB1 = gB0 + (size_t)64 * K;
    char* lA = (char*)sA + wave * 1024;   // wave-uniform LDS base
    char* lB = (char*)sB + wave * 1024;

    f32x4 acc[4][4] = {};

    for (int kt = 0; kt < K; kt += 32) {
        __builtin_amdgcn_global_load_lds((as1_void*)gA0, (as3_void*)lA, 16, 0, 0);
        __builtin_amdgcn_global_load_lds((as1_void*)gA1, (as3_void*)(lA + 4096), 16, 0, 0);
        __builtin_amdgcn_global_load_lds((as1_void*)gB0, (as3_void*)lB, 16, 0, 0);
        __builtin_amdgcn_global_load_lds((as1_void*)gB1, (as3_void*)(lB + 4096), 16, 0, 0);
        gA0 += 32; gA1 += 32; gB0 += 32; gB1 += 32;
        __syncthreads();   // drains vmcnt -> LDS data visible

        bf16x8 af[4], bfr[4];
#pragma unroll
        for (int i = 0; i < 4; ++i)
            af[i] = *(const bf16x8*)(sA + (wm + i * 16 + mr) * 32 + quad * 8);
#pragma unroll
        for (int j = 0; j < 4; ++j)
            bfr[j] = *(const bf16x8*)(sB + (wn + j * 16 + mr) * 32 + quad * 8);

#pragma unroll
        for (int i = 0; i < 4; ++i)
#pragma unroll
            for (int j = 0; j < 4; ++j)
                acc[i][j] = __builtin_amdgcn_mfma_f32_16x16x32_bf16(
                    af[i], bfr[j], acc[i][j], 0, 0, 0);
        __syncthreads();   // protect LDS before next stage
    }

    // epilogue: C/D layout col=lane&15, row=quad*4+reg
#pragma unroll
    for (int j = 0; j < 4; ++j) {
        const int gcol = bn + wn + j * 16 + mr;
        const float bv = bias[gcol];
#pragma unroll
        for (int i = 0; i < 4; ++i) {
            const int gr = bm + wm + i * 16 + quad * 4;
#pragma unroll
            for (int r = 0; r < 4; ++r) {
                const float v = acc[i][j][r] + bv;
                const size_t off = (size_t)(gr + r) * N + gcol;
                if (OUT_F32) Cf[off] = v;
                else         Cb[off] = f2bf(v);
            }
        }
    }
}

// --------------------------- neighborhood attention ------------------------
// QKV: (B*S, 3072) bf16, row = [q(1024) k(1024) v(1024)], head h at h*64.
// One wave per query; lane = head dim. out: (B*S, 1024) bf16.
__global__ __launch_bounds__(256) void attn_kernel(
    const unsigned short* __restrict__ qkv, unsigned short* __restrict__ out) {
    const int lane = threadIdx.x & 63;
    const int wave = threadIdx.x >> 6;
    const int gq = blockIdx.x * 4 + wave;       // (b*NH + h)*S + s
    const int s = gq & 8191;
    const int bh = gq >> 13;
    const int h = bh & 15;
    const int b = bh >> 4;
    const size_t qrow = (size_t)(b * 8192 + s) * 3072 + h * 64;

    const float q = bf2f(qkv[qrow + lane]);

    float sc[7];
#pragma unroll
    for (int j = 0; j < 7; ++j) {
        const int idx = s + j - 3;
        if (idx >= 0 && idx < 8192) {           // wave-uniform branch
            float p = q * bf2f(qkv[(size_t)(b * 8192 + idx) * 3072 + 1024 + h * 64 + lane]);
#pragma unroll
            for (int off = 32; off > 0; off >>= 1) p += __shfl_xor(p, off);
            sc[j] = p * 0.125f;
        } else {
            sc[j] = -1e30f;
        }
    }
    float m = sc[0];
#pragma unroll
    for (int j = 1; j < 7; ++j) m = fmaxf(m, sc[j]);
    float p[7], l = 0.f;
#pragma unroll
    for (int j = 0; j < 7; ++j) { p[j] = __expf(sc[j] - m); l += p[j]; }

    float o = 0.f;
#pragma unroll
    for (int j = 0; j < 7; ++j) {
        const int idx = s + j - 3;
        if (idx >= 0 && idx < 8192)
            o += p[j] * bf2f(qkv[(size_t)(b * 8192 + idx) * 3072 + 2048 + h * 64 + lane]);
    }
    o /= l;
    out[(size_t)(b * 8192 + s) * 1024 + h * 64 + lane] = f2bf(o);
}

// ------------------------------- launch ------------------------------------
extern "C" void kernel_launch(void* const* d_in, const int* in_sizes, int n_in,
                              void* d_out, int out_size, void* d_ws, size_t ws_size,
                              hipStream_t stream) {
    (void)in_sizes; (void)n_in; (void)out_size; (void)ws_size;
    const float* X  = (const float*)d_in[0];
    const float* wq = (const float*)d_in[1];
    const float* bq = (const float*)d_in[2];
    const float* wk = (const float*)d_in[3];
    const float* bk = (const float*)d_in[4];
    const float* wv = (const float*)d_in[5];
    const float* bv = (const float*)d_in[6];
    const float* wo = (const float*)d_in[7];
    const float* bo = (const float*)d_in[8];
    float* out = (float*)d_out;

    char* ws = (char*)d_ws;
    unsigned short* Xb    = (unsigned short*)(ws);                 // 32 MB
    unsigned short* WtQKV = (unsigned short*)(ws + 33554432);      // 6 MB
    unsigned short* WtO   = (unsigned short*)(ws + 39845888);      // 2 MB
    float*          biasQ = (float*)(ws + 41943040);               // 12 KB
    unsigned short* QKV   = (unsigned short*)(ws + 41955328);      // 96 MB
    unsigned short* AttnO = (unsigned short*)(ws + 142618624);     // 32 MB

    cast_kernel<<<16384, 256, 0, stream>>>(X, Xb, 4194304);

    dim3 tb(32, 8), tg(32, 32);
    transpose_cast<<<tg, tb, 0, stream>>>(wq, WtQKV);
    transpose_cast<<<tg, tb, 0, stream>>>(wk, WtQKV + 1024 * 1024);
    transpose_cast<<<tg, tb, 0, stream>>>(wv, WtQKV + 2 * 1024 * 1024);
    transpose_cast<<<tg, tb, 0, stream>>>(wo, WtO);
    concat_bias<<<12, 256, 0, stream>>>(bq, bk, bv, biasQ);

    // QKV: M=16384, N=3072, K=1024
    gemm_bt<0><<<dim3(24, 128), 256, 0, stream>>>(Xb, WtQKV, biasQ, nullptr, QKV, 3072, 1024);

    // attention: B*NH*S / 4 waves-per-block = 65536 blocks
    attn_kernel<<<65536, 256, 0, stream>>>(QKV, AttnO);

    // O-proj: M=16384, N=1024, K=1024, fp32 out
    gemm_bt<1><<<dim3(8, 128), 256, 0, stream>>>(AttnO, WtO, bo, out, nullptr, 1024, 1024);
}

// Round 2
// 411.713 us; speedup vs baseline: 1.3901x; 1.3901x over previous
//
#include <hip/hip_runtime.h>

// ---------------------------------------------------------------------------
// LigerFusedNeighborhoodAttention on MI355X (gfx950)
// B=2, S=8192, H=1024, NH=16, HD=64, KERNEL=7, DILATION=1, SCALE=1/8
//
// Pipeline:
//   1. cast X fp32 -> bf16
//   2. transpose+cast weights -> bf16 (B^T form for gemm_bt)
//   3. fused QKV GEMM (16384 x 3072 x 1024): epilogue splits ->
//        QK (16384 x 2048) row-major   and   Vt (2,16,64,8192) transposed
//   4. MFMA banded attention: 1 wave = 64 queries; S(64x80)=Q@K^T via 40
//      mfma_16x16x32_bf16, band mask + softmax, P -> LDS (C->A layout),
//      O(64x64)=P@V via 48 mfma, coalesced store via LDS transpose.
//   5. output GEMM (16384 x 1024 x 1024) -> d_out fp32
// ---------------------------------------------------------------------------

typedef __bf16 bf16x8 __attribute__((ext_vector_type(8)));
typedef float f32x4 __attribute__((ext_vector_type(4)));
typedef int int4v __attribute__((ext_vector_type(4)));
typedef __attribute__((address_space(1))) void as1_void;
typedef __attribute__((address_space(3))) void as3_void;

__device__ __forceinline__ float bf2f(unsigned short u) {
    union { unsigned int u; float f; } c;
    c.u = ((unsigned int)u) << 16;
    return c.f;
}
__device__ __forceinline__ unsigned short f2bf(float f) {
    union { float f; unsigned int u; } c;
    c.f = f;
    unsigned int u = c.u;
    u += 0x7fffu + ((u >> 16) & 1u);   // round-to-nearest-even
    return (unsigned short)(u >> 16);
}

// --------------------------- cast X fp32 -> bf16 ---------------------------
__global__ __launch_bounds__(256) void cast_kernel(
    const float* __restrict__ in, unsigned short* __restrict__ out, int n4) {
    int i = blockIdx.x * 256 + threadIdx.x;
    if (i < n4) {
        float4 v = ((const float4*)in)[i];
        ushort4 o;
        o.x = f2bf(v.x); o.y = f2bf(v.y); o.z = f2bf(v.z); o.w = f2bf(v.w);
        ((ushort4*)out)[i] = o;
    }
}

// ------------------- transpose+cast 1024x1024 W -> Wt bf16 -----------------
__global__ __launch_bounds__(256) void transpose_cast(
    const float* __restrict__ W, unsigned short* __restrict__ Wt) {
    __shared__ unsigned short tile[32][33];
    const int c0 = blockIdx.x * 32;
    const int r0 = blockIdx.y * 32;
    const int tx = threadIdx.x;
    const int ty = threadIdx.y;
#pragma unroll
    for (int i = 0; i < 32; i += 8)
        tile[ty + i][tx] = f2bf(W[(size_t)(r0 + ty + i) * 1024 + c0 + tx]);
    __syncthreads();
#pragma unroll
    for (int i = 0; i < 32; i += 8)
        Wt[(size_t)(c0 + ty + i) * 1024 + r0 + tx] = tile[tx][ty + i];
}

// --------------------------- bias concat (3072) ----------------------------
__global__ __launch_bounds__(256) void concat_bias(
    const float* __restrict__ a, const float* __restrict__ b,
    const float* __restrict__ c, float* __restrict__ o) {
    int i = blockIdx.x * 256 + threadIdx.x;
    if (i < 3072)
        o[i] = (i < 1024) ? a[i] : ((i < 2048) ? b[i - 1024] : c[i - 2048]);
}

// ------------------------------- MFMA GEMM ---------------------------------
// C(M,N) = A(M,K)*Bt(N,K)^T + bias.
// MODE 0: fp32 store to Cf (ldc = N).
// MODE 1: QKV split: col<2048 -> bf16 QK[row*2048+col]; col>=2048 -> bf16
//         Vt[b][h][d][s] (transposed V).
template <int MODE>
__global__ __launch_bounds__(256) void gemm_bt(
    const unsigned short* __restrict__ A, const unsigned short* __restrict__ Bt,
    const float* __restrict__ bias, float* __restrict__ Cf,
    unsigned short* __restrict__ Cb, unsigned short* __restrict__ Vt,
    int N, int K) {
    __shared__ unsigned short sA[128 * 32];
    __shared__ unsigned short sB[128 * 32];
    const int tid = threadIdx.x;
    const int lane = tid & 63;
    const int wave = tid >> 6;
    const int bm = blockIdx.y * 128;
    const int bn = blockIdx.x * 128;
    const int wm = (wave >> 1) * 64;
    const int wn = (wave & 1) * 64;
    const int quad = lane >> 4;
    const int mr = lane & 15;

    const unsigned short* gA0 = A + (size_t)(bm + (tid >> 2)) * K + (tid & 3) * 8;
    const unsigned short* gA1 = gA0 + (size_t)64 * K;
    const unsigned short* gB0 = Bt + (size_t)(bn + (tid >> 2)) * K + (tid & 3) * 8;
    const unsigned short* gB1 = gB0 + (size_t)64 * K;
    char* lA = (char*)sA + wave * 1024;
    char* lB = (char*)sB + wave * 1024;

    f32x4 acc[4][4] = {};

    for (int kt = 0; kt < K; kt += 32) {
        __builtin_amdgcn_global_load_lds((as1_void*)gA0, (as3_void*)lA, 16, 0, 0);
        __builtin_amdgcn_global_load_lds((as1_void*)gA1, (as3_void*)(lA + 4096), 16, 0, 0);
        __builtin_amdgcn_global_load_lds((as1_void*)gB0, (as3_void*)lB, 16, 0, 0);
        __builtin_amdgcn_global_load_lds((as1_void*)gB1, (as3_void*)(lB + 4096), 16, 0, 0);
        gA0 += 32; gA1 += 32; gB0 += 32; gB1 += 32;
        __syncthreads();

        bf16x8 af[4], bfr[4];
#pragma unroll
        for (int i = 0; i < 4; ++i)
            af[i] = *(const bf16x8*)(sA + (wm + i * 16 + mr) * 32 + quad * 8);
#pragma unroll
        for (int j = 0; j < 4; ++j)
            bfr[j] = *(const bf16x8*)(sB + (wn + j * 16 + mr) * 32 + quad * 8);

#pragma unroll
        for (int i = 0; i < 4; ++i)
#pragma unroll
            for (int j = 0; j < 4; ++j)
                acc[i][j] = __builtin_amdgcn_mfma_f32_16x16x32_bf16(
                    af[i], bfr[j], acc[i][j], 0, 0, 0);
        __syncthreads();
    }

    // epilogue: C/D layout col=lane&15, row=quad*4+reg
#pragma unroll
    for (int j = 0; j < 4; ++j) {
        const int gcol = bn + wn + j * 16 + mr;
        const float bv = bias[gcol];
#pragma unroll
        for (int i = 0; i < 4; ++i) {
            const int gr = bm + wm + i * 16 + quad * 4;
#pragma unroll
            for (int r = 0; r < 4; ++r) {
                const float v = acc[i][j][r] + bv;
                const int row = gr + r;
                if (MODE == 0) {
                    Cf[(size_t)row * N + gcol] = v;
                } else {
                    if (gcol < 2048) {   // block-uniform per j (16-col groups)
                        Cb[(size_t)row * 2048 + gcol] = f2bf(v);
                    } else {
                        const int hv = (gcol - 2048) >> 6;
                        const int dv = (gcol - 2048) & 63;
                        const int bb = row >> 13;
                        const int ss = row & 8191;
                        Vt[((size_t)(bb * 16 + hv) * 64 + dv) * 8192 + ss] = f2bf(v);
                    }
                }
            }
        }
    }
}

// --------------------------- MFMA banded attention -------------------------
// QK: (16384, 2048) bf16 rows [q(1024) k(1024)]; Vt: (2,16,64,8192) bf16.
// 1 wave = 64 consecutive queries of one (b,h). Window 96 wide, origin
// win0 = s0-8 (8-aligned -> 16B-aligned frag loads); band rel = k-m in [5,11].
__global__ __launch_bounds__(256) void attn_mfma(
    const unsigned short* __restrict__ QK, const unsigned short* __restrict__ Vt,
    unsigned short* __restrict__ out) {
    __shared__ unsigned short sP[4][64 * 104];   // 13312 B per wave
    const int tid = threadIdx.x;
    const int lane = tid & 63;
    const int wave = tid >> 6;
    const int quad = lane >> 4;
    const int cc = lane & 15;
    const int w = blockIdx.x * 4 + wave;
    const int b = w >> 11;                 // 2048 waves per batch
    const int h = (w >> 7) & 15;
    const int st = w & 127;
    const int s0 = st << 6;
    const int win0 = s0 - 8;
    const size_t tokBase = (size_t)b * 8192;
    unsigned short* P = sP[wave];

    // zero P region (13312 B = 13 x 64 lanes x 16 B)
    {
        int4v z = {0, 0, 0, 0};
#pragma unroll
        for (int i = 0; i < 13; ++i)
            *(int4v*)(P + i * 512 + lane * 8) = z;
    }

    // ---- S = Q @ K^T  (64 x 80) ----
    f32x4 accS[4][5] = {};
#pragma unroll
    for (int kc = 0; kc < 2; ++kc) {
        bf16x8 qf[4], kf[5];
#pragma unroll
        for (int mt = 0; mt < 4; ++mt)
            qf[mt] = *(const bf16x8*)(QK + (tokBase + s0 + mt * 16 + cc) * 2048
                                      + h * 64 + kc * 32 + quad * 8);
#pragma unroll
        for (int nt = 0; nt < 5; ++nt) {
            int row = win0 + nt * 16 + cc;
            row = row < 0 ? 0 : (row > 8191 ? 8191 : row);   // clamped rows masked later
            kf[nt] = *(const bf16x8*)(QK + (tokBase + row) * 2048
                                      + 1024 + h * 64 + kc * 32 + quad * 8);
        }
#pragma unroll
        for (int mt = 0; mt < 4; ++mt)
#pragma unroll
            for (int nt = 0; nt < 5; ++nt)
                accS[mt][nt] = __builtin_amdgcn_mfma_f32_16x16x32_bf16(
                    qf[mt], kf[nt], accS[mt][nt], 0, 0, 0);
    }

    // ---- band mask + softmax (normalized), P -> LDS in A-layout ----
    const float NEG = -__builtin_inff();
#pragma unroll
    for (int mt = 0; mt < 4; ++mt) {
#pragma unroll
        for (int r = 0; r < 4; ++r) {
            const int mrow = mt * 16 + quad * 4 + r;
            float v[5];
#pragma unroll
            for (int nt = 0; nt < 5; ++nt) {
                const int k = nt * 16 + cc;
                const int rel = k - mrow;
                const int sidx = win0 + k;
                const bool ok = (rel >= 5) & (rel <= 11) & (sidx >= 0) & (sidx < 8192);
                v[nt] = ok ? accS[mt][nt][r] * 0.125f : NEG;
            }
            float mx = v[0];
#pragma unroll
            for (int nt = 1; nt < 5; ++nt) mx = fmaxf(mx, v[nt]);
#pragma unroll
            for (int off = 8; off >= 1; off >>= 1) mx = fmaxf(mx, __shfl_xor(mx, off));
            float p[5], sum = 0.f;
#pragma unroll
            for (int nt = 0; nt < 5; ++nt) {
                p[nt] = __builtin_amdgcn_exp2f((v[nt] - mx) * 1.44269504f);
                sum += p[nt];
            }
#pragma unroll
            for (int off = 8; off >= 1; off >>= 1) sum += __shfl_xor(sum, off);
            const float inv = __builtin_amdgcn_rcpf(sum);
#pragma unroll
            for (int nt = 0; nt < 5; ++nt)
                P[mrow * 104 + nt * 16 + cc] = f2bf(p[nt] * inv);
        }
    }

    // ---- O = P @ V  (64 x 64), K-dim padded to 96 ----
    f32x4 accO[4][4] = {};
#pragma unroll
    for (int kc = 0; kc < 3; ++kc) {
        bf16x8 pf[4], vf[4];
#pragma unroll
        for (int mt = 0; mt < 4; ++mt)
            pf[mt] = *(const bf16x8*)(P + (mt * 16 + cc) * 104 + kc * 32 + quad * 8);
        {
            int pos = win0 + kc * 32 + quad * 8;
            pos = pos < 0 ? 0 : (pos > 8184 ? 8184 : pos);   // clamped pos hit P==0
#pragma unroll
            for (int nt = 0; nt < 4; ++nt)
                vf[nt] = *(const bf16x8*)(Vt + ((size_t)(b * 16 + h) * 64 + nt * 16 + cc) * 8192 + pos);
        }
#pragma unroll
        for (int mt = 0; mt < 4; ++mt)
#pragma unroll
            for (int nt = 0; nt < 4; ++nt)
                accO[mt][nt] = __builtin_amdgcn_mfma_f32_16x16x32_bf16(
                    pf[mt], vf[nt], accO[mt][nt], 0, 0, 0);
    }

    // ---- store: C-layout -> LDS (stride 72) -> coalesced global ----
#pragma unroll
    for (int mt = 0; mt < 4; ++mt)
#pragma unroll
        for (int nt = 0; nt < 4; ++nt)
#pragma unroll
            for (int r = 0; r < 4; ++r)
                P[(mt * 16 + quad * 4 + r) * 72 + nt * 16 + cc] = f2bf(accO[mt][nt][r]);

#pragma unroll
    for (int pass = 0; pass < 8; ++pass) {
        const int row = pass * 8 + (lane >> 3);
        const int ch = lane & 7;
        int4v vv = *(const int4v*)(P + row * 72 + ch * 8);
        *(int4v*)(out + (tokBase + s0 + row) * 1024 + h * 64 + ch * 8) = vv;
    }
}

// ------------------------------- launch ------------------------------------
extern "C" void kernel_launch(void* const* d_in, const int* in_sizes, int n_in,
                              void* d_out, int out_size, void* d_ws, size_t ws_size,
                              hipStream_t stream) {
    (void)in_sizes; (void)n_in; (void)out_size; (void)ws_size;
    const float* X  = (const float*)d_in[0];
    const float* wq = (const float*)d_in[1];
    const float* bq = (const float*)d_in[2];
    const float* wk = (const float*)d_in[3];
    const float* bk = (const float*)d_in[4];
    const float* wv = (const float*)d_in[5];
    const float* bv = (const float*)d_in[6];
    const float* wo = (const float*)d_in[7];
    const float* bo = (const float*)d_in[8];
    float* out = (float*)d_out;

    char* ws = (char*)d_ws;
    unsigned short* Xb    = (unsigned short*)(ws);                 // 32 MB
    unsigned short* WtQKV = (unsigned short*)(ws + 33554432);      // 6 MB
    unsigned short* WtO   = (unsigned short*)(ws + 39845888);      // 2 MB
    unsigned short* QK    = (unsigned short*)(ws + 41943040);      // 64 MB
    unsigned short* Vt    = (unsigned short*)(ws + 109051904);     // 32 MB
    unsigned short* AttnO = (unsigned short*)(ws + 142606336);     // 32 MB
    float*          biasQ = (float*)(ws + 176160768);              // 12 KB

    cast_kernel<<<16384, 256, 0, stream>>>(X, Xb, 4194304);

    dim3 tb(32, 8), tg(32, 32);
    transpose_cast<<<tg, tb, 0, stream>>>(wq, WtQKV);
    transpose_cast<<<tg, tb, 0, stream>>>(wk, WtQKV + 1024 * 1024);
    transpose_cast<<<tg, tb, 0, stream>>>(wv, WtQKV + 2 * 1024 * 1024);
    transpose_cast<<<tg, tb, 0, stream>>>(wo, WtO);
    concat_bias<<<12, 256, 0, stream>>>(bq, bk, bv, biasQ);

    // QKV: M=16384, N=3072, K=1024 -> QK + Vt
    gemm_bt<1><<<dim3(24, 128), 256, 0, stream>>>(Xb, WtQKV, biasQ, nullptr, QK, Vt, 3072, 1024);

    // attention: 4096 waves = 1024 blocks
    attn_mfma<<<1024, 256, 0, stream>>>(QK, Vt, AttnO);

    // O-proj: M=16384, N=1024, K=1024, fp32 out
    gemm_bt<0><<<dim3(8, 128), 256, 0, stream>>>(AttnO, WtO, bo, out, nullptr, nullptr, 1024, 1024);
}

// Round 3
// 353.881 us; speedup vs baseline: 1.6172x; 1.1634x over previous
//
#include <hip/hip_runtime.h>

// ---------------------------------------------------------------------------
// LigerFusedNeighborhoodAttention on MI355X (gfx950)
// B=2, S=8192, H=1024, NH=16, HD=64, KERNEL=7, DILATION=1, SCALE=1/8
//
// Pipeline:
//   1. cast X fp32 -> bf16
//   2. transpose+cast weights -> bf16 (B^T form for gemm_bt)
//   3. fused QKV GEMM (16384 x 3072 x 1024), BK=64, swizzled staging:
//        epilogue: QK blocks -> row-major bf16; V blocks -> Vt via LDS
//        transpose (coalesced 8B stores), Vt (2,16,64,8192)
//   4. MFMA banded attention (unchanged from round 2)
//   5. output GEMM (16384 x 1024 x 1024) -> d_out fp32
// ---------------------------------------------------------------------------

typedef __bf16 bf16x8 __attribute__((ext_vector_type(8)));
typedef float f32x4 __attribute__((ext_vector_type(4)));
typedef int int4v __attribute__((ext_vector_type(4)));
typedef __attribute__((address_space(1))) void as1_void;
typedef __attribute__((address_space(3))) void as3_void;

__device__ __forceinline__ float bf2f(unsigned short u) {
    union { unsigned int u; float f; } c;
    c.u = ((unsigned int)u) << 16;
    return c.f;
}
__device__ __forceinline__ unsigned short f2bf(float f) {
    union { float f; unsigned int u; } c;
    c.f = f;
    unsigned int u = c.u;
    u += 0x7fffu + ((u >> 16) & 1u);   // round-to-nearest-even
    return (unsigned short)(u >> 16);
}

// --------------------------- cast X fp32 -> bf16 ---------------------------
__global__ __launch_bounds__(256) void cast_kernel(
    const float* __restrict__ in, unsigned short* __restrict__ out, int n4) {
    int i = blockIdx.x * 256 + threadIdx.x;
    if (i < n4) {
        float4 v = ((const float4*)in)[i];
        ushort4 o;
        o.x = f2bf(v.x); o.y = f2bf(v.y); o.z = f2bf(v.z); o.w = f2bf(v.w);
        ((ushort4*)out)[i] = o;
    }
}

// ------------------- transpose+cast 1024x1024 W -> Wt bf16 -----------------
__global__ __launch_bounds__(256) void transpose_cast(
    const float* __restrict__ W, unsigned short* __restrict__ Wt) {
    __shared__ unsigned short tile[32][33];
    const int c0 = blockIdx.x * 32;
    const int r0 = blockIdx.y * 32;
    const int tx = threadIdx.x;
    const int ty = threadIdx.y;
#pragma unroll
    for (int i = 0; i < 32; i += 8)
        tile[ty + i][tx] = f2bf(W[(size_t)(r0 + ty + i) * 1024 + c0 + tx]);
    __syncthreads();
#pragma unroll
    for (int i = 0; i < 32; i += 8)
        Wt[(size_t)(c0 + ty + i) * 1024 + r0 + tx] = tile[tx][ty + i];
}

// --------------------------- bias concat (3072) ----------------------------
__global__ __launch_bounds__(256) void concat_bias(
    const float* __restrict__ a, const float* __restrict__ b,
    const float* __restrict__ c, float* __restrict__ o) {
    int i = blockIdx.x * 256 + threadIdx.x;
    if (i < 3072)
        o[i] = (i < 1024) ? a[i] : ((i < 2048) ? b[i - 1024] : c[i - 2048]);
}

// ------------------------------- MFMA GEMM ---------------------------------
// C(M,N) = A(M,K)*Bt(N,K)^T + bias.  BK=64, 128x128 tile, 4 waves.
// Staging: thread covers 4 16B chunks per tile; source column XOR-swizzled
// by (row&7) so LDS frag reads (128B row stride) are bank-conflict-free.
// MODE 0: fp32 store to Cf (ldc = N).
// MODE 1: col<2048 -> bf16 QK row-major; col>=2048 -> Vt[b][h][d][s] via
//         wave-private LDS transpose + coalesced 8B stores.
template <int MODE>
__global__ __launch_bounds__(256) void gemm_bt(
    const unsigned short* __restrict__ A, const unsigned short* __restrict__ Bt,
    const float* __restrict__ bias, float* __restrict__ Cf,
    unsigned short* __restrict__ Cb, unsigned short* __restrict__ Vt,
    int N, int K) {
    __shared__ unsigned short smem[16384];     // sA = smem[0:8192), sB = [8192:16384)
    const int tid = threadIdx.x;
    const int lane = tid & 63;
    const int wave = tid >> 6;
    const int bm = blockIdx.y * 128;
    const int bn = blockIdx.x * 128;
    const int wm = (wave >> 1) * 64;
    const int wn = (wave & 1) * 64;
    const int quad = lane >> 4;
    const int mr = lane & 15;

    // staging chunk ids: q = (k*4+wave)*64 + lane, k=0..3 (covers 1024 chunks)
    const unsigned short* gA[4];
    const unsigned short* gB[4];
    char* lA[4];
    char* lB[4];
#pragma unroll
    for (int k = 0; k < 4; ++k) {
        const int q = (k * 4 + wave) * 64 + lane;
        const int row = q >> 3;
        const int c8 = (q & 7) ^ (row & 7);    // source-column swizzle
        gA[k] = A + (size_t)(bm + row) * K + c8 * 8;
        gB[k] = Bt + (size_t)(bn + row) * K + c8 * 8;
        lA[k] = (char*)smem + (size_t)(k * 4 + wave) * 1024;   // + lane*16 implicit
        lB[k] = (char*)smem + 16384 + (size_t)(k * 4 + wave) * 1024;
    }

    f32x4 acc[4][4] = {};

    for (int kt = 0; kt < K; kt += 64) {
#pragma unroll
        for (int k = 0; k < 4; ++k) {
            __builtin_amdgcn_global_load_lds((as1_void*)gA[k], (as3_void*)lA[k], 16, 0, 0);
            __builtin_amdgcn_global_load_lds((as1_void*)gB[k], (as3_void*)lB[k], 16, 0, 0);
            gA[k] += 64; gB[k] += 64;
        }
        __syncthreads();   // drains vmcnt -> LDS data visible

#pragma unroll
        for (int kk = 0; kk < 2; ++kk) {
            bf16x8 af[4], bfr[4];
#pragma unroll
            for (int i = 0; i < 4; ++i) {
                const int R = wm + i * 16 + mr;
                const int c8 = (kk * 4 + quad) ^ (mr & 7);
                af[i] = *(const bf16x8*)(smem + R * 64 + c8 * 8);
            }
#pragma unroll
            for (int j = 0; j < 4; ++j) {
                const int R = wn + j * 16 + mr;
                const int c8 = (kk * 4 + quad) ^ (mr & 7);
                bfr[j] = *(const bf16x8*)(smem + 8192 + R * 64 + c8 * 8);
            }
#pragma unroll
            for (int i = 0; i < 4; ++i)
#pragma unroll
                for (int j = 0; j < 4; ++j)
                    acc[i][j] = __builtin_amdgcn_mfma_f32_16x16x32_bf16(
                        af[i], bfr[j], acc[i][j], 0, 0, 0);
        }
        __syncthreads();   // protect LDS before next stage
    }

    // ---------------- epilogue: C/D layout col=lane&15, row=quad*4+reg -----
    if (MODE == 0 || bn < 2048) {
#pragma unroll
        for (int j = 0; j < 4; ++j) {
            const int gcol = bn + wn + j * 16 + mr;
            const float bv = bias[gcol];
#pragma unroll
            for (int i = 0; i < 4; ++i) {
                const int gr = bm + wm + i * 16 + quad * 4;
#pragma unroll
                for (int r = 0; r < 4; ++r) {
                    const float v = acc[i][j][r] + bv;
                    if (MODE == 0) Cf[(size_t)(gr + r) * N + gcol] = v;
                    else           Cb[(size_t)(gr + r) * 2048 + gcol] = f2bf(v);
                }
            }
        }
    } else {
        // V block: wave-private LDS transpose, 16 d-cols (one j) at a time.
        unsigned short* ep = smem + wave * 2048;   // 4 KB per wave (uses 1088)
        const int bb = (bm + wm) >> 13;
        const int ssb = (bm + wm) & 8191;
        const int lr = ((lane & 15) == lane ? 0 : 0);  // (no-op; keep compiler calm)
#pragma unroll
        for (int j = 0; j < 4; ++j) {
            const int gcol = bn + wn + j * 16 + mr;
            const float bv = bias[gcol];
#pragma unroll
            for (int i = 0; i < 4; ++i)
#pragma unroll
                for (int r = 0; r < 4; ++r)
                    ep[mr * 68 + i * 16 + quad * 4 + r] = f2bf(acc[i][j][r] + bv);
            // rows separated by 8192*2B in Vt; read LDS + coalesced 8B stores
            const size_t vrow0 = (size_t)(bb * 1024 + (bn - 2048) + wn + j * 16);
#pragma unroll
            for (int p = 0; p < 4; ++p) {
                const int dr = (p * 64 + lane) >> 4;    // 0..15 local d row
                const int ch = lane & 15;               // 4-short chunk in s
                uint2 val = *(const uint2*)(ep + dr * 68 + ch * 4);
                *(uint2*)(Vt + (vrow0 + dr) * 8192 + ssb + ch * 4) = val;
            }
        }
        (void)lr;
    }
}

// --------------------------- MFMA banded attention -------------------------
// QK: (16384, 2048) bf16 rows [q(1024) k(1024)]; Vt: (2,16,64,8192) bf16.
// 1 wave = 64 consecutive queries of one (b,h). Window 96 wide, origin
// win0 = s0-8 (8-aligned -> 16B-aligned frag loads); band rel = k-m in [5,11].
__global__ __launch_bounds__(256) void attn_mfma(
    const unsigned short* __restrict__ QK, const unsigned short* __restrict__ Vt,
    unsigned short* __restrict__ out) {
    __shared__ unsigned short sP[4][64 * 104];   // 13312 B per wave
    const int tid = threadIdx.x;
    const int lane = tid & 63;
    const int wave = tid >> 6;
    const int quad = lane >> 4;
    const int cc = lane & 15;
    const int w = blockIdx.x * 4 + wave;
    const int b = w >> 11;                 // 2048 waves per batch
    const int h = (w >> 7) & 15;
    const int st = w & 127;
    const int s0 = st << 6;
    const int win0 = s0 - 8;
    const size_t tokBase = (size_t)b * 8192;
    unsigned short* P = sP[wave];

    // zero P region (13312 B = 13 x 64 lanes x 16 B)
    {
        int4v z = {0, 0, 0, 0};
#pragma unroll
        for (int i = 0; i < 13; ++i)
            *(int4v*)(P + i * 512 + lane * 8) = z;
    }

    // ---- S = Q @ K^T  (64 x 80) ----
    f32x4 accS[4][5] = {};
#pragma unroll
    for (int kc = 0; kc < 2; ++kc) {
        bf16x8 qf[4], kf[5];
#pragma unroll
        for (int mt = 0; mt < 4; ++mt)
            qf[mt] = *(const bf16x8*)(QK + (tokBase + s0 + mt * 16 + cc) * 2048
                                      + h * 64 + kc * 32 + quad * 8);
#pragma unroll
        for (int nt = 0; nt < 5; ++nt) {
            int row = win0 + nt * 16 + cc;
            row = row < 0 ? 0 : (row > 8191 ? 8191 : row);   // clamped rows masked later
            kf[nt] = *(const bf16x8*)(QK + (tokBase + row) * 2048
                                      + 1024 + h * 64 + kc * 32 + quad * 8);
        }
#pragma unroll
        for (int mt = 0; mt < 4; ++mt)
#pragma unroll
            for (int nt = 0; nt < 5; ++nt)
                accS[mt][nt] = __builtin_amdgcn_mfma_f32_16x16x32_bf16(
                    qf[mt], kf[nt], accS[mt][nt], 0, 0, 0);
    }

    // ---- band mask + softmax (normalized), P -> LDS in A-layout ----
    const float NEG = -__builtin_inff();
#pragma unroll
    for (int mt = 0; mt < 4; ++mt) {
#pragma unroll
        for (int r = 0; r < 4; ++r) {
            const int mrow = mt * 16 + quad * 4 + r;
            float v[5];
#pragma unroll
            for (int nt = 0; nt < 5; ++nt) {
                const int k = nt * 16 + cc;
                const int rel = k - mrow;
                const int sidx = win0 + k;
                const bool ok = (rel >= 5) & (rel <= 11) & (sidx >= 0) & (sidx < 8192);
                v[nt] = ok ? accS[mt][nt][r] * 0.125f : NEG;
            }
            float mx = v[0];
#pragma unroll
            for (int nt = 1; nt < 5; ++nt) mx = fmaxf(mx, v[nt]);
#pragma unroll
            for (int off = 8; off >= 1; off >>= 1) mx = fmaxf(mx, __shfl_xor(mx, off));
            float p[5], sum = 0.f;
#pragma unroll
            for (int nt = 0; nt < 5; ++nt) {
                p[nt] = __builtin_amdgcn_exp2f((v[nt] - mx) * 1.44269504f);
                sum += p[nt];
            }
#pragma unroll
            for (int off = 8; off >= 1; off >>= 1) sum += __shfl_xor(sum, off);
            const float inv = __builtin_amdgcn_rcpf(sum);
#pragma unroll
            for (int nt = 0; nt < 5; ++nt)
                P[mrow * 104 + nt * 16 + cc] = f2bf(p[nt] * inv);
        }
    }

    // ---- O = P @ V  (64 x 64), K-dim padded to 96 ----
    f32x4 accO[4][4] = {};
#pragma unroll
    for (int kc = 0; kc < 3; ++kc) {
        bf16x8 pf[4], vf[4];
#pragma unroll
        for (int mt = 0; mt < 4; ++mt)
            pf[mt] = *(const bf16x8*)(P + (mt * 16 + cc) * 104 + kc * 32 + quad * 8);
        {
            int pos = win0 + kc * 32 + quad * 8;
            pos = pos < 0 ? 0 : (pos > 8184 ? 8184 : pos);   // clamped pos hit P==0
#pragma unroll
            for (int nt = 0; nt < 4; ++nt)
                vf[nt] = *(const bf16x8*)(Vt + ((size_t)(b * 16 + h) * 64 + nt * 16 + cc) * 8192 + pos);
        }
#pragma unroll
        for (int mt = 0; mt < 4; ++mt)
#pragma unroll
            for (int nt = 0; nt < 4; ++nt)
                accO[mt][nt] = __builtin_amdgcn_mfma_f32_16x16x32_bf16(
                    pf[mt], vf[nt], accO[mt][nt], 0, 0, 0);
    }

    // ---- store: C-layout -> LDS (stride 72) -> coalesced global ----
#pragma unroll
    for (int mt = 0; mt < 4; ++mt)
#pragma unroll
        for (int nt = 0; nt < 4; ++nt)
#pragma unroll
            for (int r = 0; r < 4; ++r)
                P[(mt * 16 + quad * 4 + r) * 72 + nt * 16 + cc] = f2bf(accO[mt][nt][r]);

#pragma unroll
    for (int pass = 0; pass < 8; ++pass) {
        const int row = pass * 8 + (lane >> 3);
        const int ch = lane & 7;
        int4v vv = *(const int4v*)(P + row * 72 + ch * 8);
        *(int4v*)(out + (tokBase + s0 + row) * 1024 + h * 64 + ch * 8) = vv;
    }
}

// ------------------------------- launch ------------------------------------
extern "C" void kernel_launch(void* const* d_in, const int* in_sizes, int n_in,
                              void* d_out, int out_size, void* d_ws, size_t ws_size,
                              hipStream_t stream) {
    (void)in_sizes; (void)n_in; (void)out_size; (void)ws_size;
    const float* X  = (const float*)d_in[0];
    const float* wq = (const float*)d_in[1];
    const float* bq = (const float*)d_in[2];
    const float* wk = (const float*)d_in[3];
    const float* bk = (const float*)d_in[4];
    const float* wv = (const float*)d_in[5];
    const float* bv = (const float*)d_in[6];
    const float* wo = (const float*)d_in[7];
    const float* bo = (const float*)d_in[8];
    float* out = (float*)d_out;

    char* ws = (char*)d_ws;
    unsigned short* Xb    = (unsigned short*)(ws);                 // 32 MB
    unsigned short* WtQKV = (unsigned short*)(ws + 33554432);      // 6 MB
    unsigned short* WtO   = (unsigned short*)(ws + 39845888);      // 2 MB
    unsigned short* QK    = (unsigned short*)(ws + 41943040);      // 64 MB
    unsigned short* Vt    = (unsigned short*)(ws + 109051904);     // 32 MB
    unsigned short* AttnO = (unsigned short*)(ws + 142606336);     // 32 MB
    float*          biasQ = (float*)(ws + 176160768);              // 12 KB

    cast_kernel<<<16384, 256, 0, stream>>>(X, Xb, 4194304);

    dim3 tb(32, 8), tg(32, 32);
    transpose_cast<<<tg, tb, 0, stream>>>(wq, WtQKV);
    transpose_cast<<<tg, tb, 0, stream>>>(wk, WtQKV + 1024 * 1024);
    transpose_cast<<<tg, tb, 0, stream>>>(wv, WtQKV + 2 * 1024 * 1024);
    transpose_cast<<<tg, tb, 0, stream>>>(wo, WtO);
    concat_bias<<<12, 256, 0, stream>>>(bq, bk, bv, biasQ);

    // QKV: M=16384, N=3072, K=1024 -> QK + Vt
    gemm_bt<1><<<dim3(24, 128), 256, 0, stream>>>(Xb, WtQKV, biasQ, nullptr, QK, Vt, 3072, 1024);

    // attention: 4096 waves = 1024 blocks
    attn_mfma<<<1024, 256, 0, stream>>>(QK, Vt, AttnO);

    // O-proj: M=16384, N=1024, K=1024, fp32 out
    gemm_bt<0><<<dim3(8, 128), 256, 0, stream>>>(AttnO, WtO, bo, out, nullptr, nullptr, 1024, 1024);
}